// Round 2
// baseline (178.603 us; speedup 1.0000x reference)
//
#include <hip/hip_runtime.h>
#include <stdint.h>

typedef unsigned long long u64;

#define NCAND   4096
#define M2      8192            // 2N
#define NWORDS  128             // M2/64
#define SCORE_T 0.5f
#define IOU_T   0.5f
#define ITERS   16              // fixpoint iterations (even -> result lands in keepA)
#define JSPLIT  8               // j-range splits for the counting sort

// ---------------- workspace layout (bytes) ----------------
#define OFF_HDR     0                          // int hdr[16]: [0]=V (atomicMax), [1]=maxcoord f32 bits (atomicMax)
#define OFF_KEEPA   64                         // u64[128]
#define OFF_KEEPB   (OFF_KEEPA + 1024)         // u64[128]
#define OFF_SVALID  (OFF_KEEPB + 1024)         // u64[128]
#define OFF_KEYS    4096                       // u64[8192]  = 64 KB
#define OFF_PART    (OFF_KEYS + 65536)         // int[JSPLIT][8192] = 256 KB
#define OFF_OAREA   (OFF_PART + JSPLIT*32768)  // float[8192]
#define OFF_SSCORE  (OFF_OAREA + 32768)        // float[8192] sorted original scores
#define OFF_SLABEL  (OFF_SSCORE + 32768)       // int[8192]   sorted labels
#define OFF_SB      (OFF_SLABEL + 32768)       // float4[8192] sorted boxes
#define OFF_OBOX    (OFF_SB + 131072)          // float4[8192] sorted offset boxes
#define OFF_MASK    (OFF_OBOX + 131072)        // u64[8192][128] lower-triangle conflict mask (8 MB)
// total ≈ 8.7 MiB

__device__ __forceinline__ unsigned order_key(float f) {
    unsigned u = __float_as_uint(f);
    return (u & 0x80000000u) ? ~u : (u | 0x80000000u);  // ascending uint == ascending float
}

__device__ __forceinline__ float get_width(const int* widthp) {
    int wi = widthp[0];
    // robust to the harness storing the Python scalar as int32 or float32
    return (wi > 0 && wi < 1000000) ? (float)wi : __int_as_float(wi);
}

// Recompute the combined (flip-adjusted) candidate `idx` straight from inputs.
__device__ __forceinline__ void fetch_cand(int idx, const float* b1, const float* b2,
                                           const float* s1, const float* s2,
                                           const int* l1, const int* l2, float wf,
                                           float& x1, float& y1, float& x2, float& y2,
                                           float& sc, int& lb) {
#pragma clang fp contract(off)
    if (idx < NCAND) {
        x1 = b1[idx*4+0]; y1 = b1[idx*4+1]; x2 = b1[idx*4+2]; y2 = b1[idx*4+3];
        sc = s1[idx]; lb = l1[idx];
    } else {
        int m = idx - NCAND;
        float bx1 = b2[m*4+0], by1 = b2[m*4+1], bx2 = b2[m*4+2], by2 = b2[m*4+3];
        x1 = wf - bx2; y1 = by1; x2 = wf - bx1; y2 = by2;   // undo hflip, same IEEE ops as ref
        sc = s2[m]; lb = l2[m];
    }
}

// ---------------- kernel 1: keys + global max coordinate ----------------
extern "C" __global__ __launch_bounds__(512)
void k_build(const float* __restrict__ b1, const float* __restrict__ b2,
             const float* __restrict__ s1, const float* __restrict__ s2,
             const int* __restrict__ l1, const int* __restrict__ l2,
             const int* __restrict__ widthp, char* __restrict__ ws)
{
#pragma clang fp contract(off)
    const int e = blockIdx.x * 512 + threadIdx.x;
    const float wf = get_width(widthp);
    float x1, y1, x2, y2, sc; int lb;
    fetch_cand(e, b1, b2, s1, s2, l1, l2, wf, x1, y1, x2, y2, sc, lb);

    float lmax = fmaxf(fmaxf(x1, y1), fmaxf(x2, y2));   // coords >= 0 (clipped)
    for (int d = 32; d > 0; d >>= 1) lmax = fmaxf(lmax, __shfl_xor(lmax, d));
    if ((threadIdx.x & 63) == 0)
        atomicMax(((int*)(ws + OFF_HDR)) + 1, __float_as_int(lmax));  // poison 0xAA.. < 0, safe

    bool valid = sc >= SCORE_T;
    float s = valid ? sc : -1.0f;
    u64 key = ((u64)order_key(-s) << 32) | (unsigned)e;  // low bits = idx -> stable argsort
    ((u64*)(ws + OFF_KEYS))[e] = key;
}

// ---------------- kernel 2: counting sort, partial ranks ----------------
// grid (32, JSPLIT) x 256: block (bx,by) counts keys[j0..j0+1024) < key_i for i in bx's range
extern "C" __global__ __launch_bounds__(256)
void k_count(char* __restrict__ ws)
{
    __shared__ u64 tile[1024];
    const u64* keys = (const u64*)(ws + OFF_KEYS);
    const int i = blockIdx.x * 256 + threadIdx.x;
    const u64 mykey = keys[i];
    const int j0 = blockIdx.y * (M2 / JSPLIT);
    for (int q = threadIdx.x; q < M2 / JSPLIT; q += 256) tile[q] = keys[j0 + q];
    __syncthreads();
    int cnt = 0;
#pragma unroll 8
    for (int q = 0; q < M2 / JSPLIT; ++q) cnt += (tile[q] < mykey) ? 1 : 0;
    ((int*)(ws + OFF_PART))[blockIdx.y * M2 + i] = cnt;
}

// ---------------- kernel 3: combine ranks + scatter sorted arrays ----------------
extern "C" __global__ __launch_bounds__(1024)
void k_scatter(const float* __restrict__ b1, const float* __restrict__ b2,
               const float* __restrict__ s1, const float* __restrict__ s2,
               const int* __restrict__ l1, const int* __restrict__ l2,
               const int* __restrict__ widthp, char* __restrict__ ws)
{
#pragma clang fp contract(off)
    const int i = blockIdx.x * 1024 + threadIdx.x;
    const int* part = (const int*)(ws + OFF_PART);
    int rank = 0;
#pragma unroll
    for (int sp = 0; sp < JSPLIT; ++sp) rank += part[sp * M2 + i];

    const float wf = get_width(widthp);
    const float maxc = __int_as_float(((const int*)(ws + OFF_HDR))[1]) + 1.0f; // jnp.max(boxes)+1.0
    float x1, y1, x2, y2, sc; int lb;
    fetch_cand(i, b1, b2, s1, s2, l1, l2, wf, x1, y1, x2, y2, sc, lb);

    float off = (float)lb * maxc;               // one product then 4 adds, like ref
    float ox1 = x1 + off, oy1 = y1 + off, ox2 = x2 + off, oy2 = y2 + off;
    float area = (ox2 - ox1) * (oy2 - oy1);     // area of OFFSET boxes, like ref

    ((float4*)(ws + OFF_SB))[rank]   = make_float4(x1, y1, x2, y2);
    ((float4*)(ws + OFF_OBOX))[rank] = make_float4(ox1, oy1, ox2, oy2);
    ((float*)(ws + OFF_OAREA))[rank]  = area;
    ((float*)(ws + OFF_SSCORE))[rank] = sc;
    ((int*)(ws + OFF_SLABEL))[rank]   = lb;
}

// ---------------- kernel 4: valid bitmask in sorted order + V ----------------
extern "C" __global__ __launch_bounds__(1024)
void k_valid(char* __restrict__ ws)
{
    const int p = blockIdx.x * 1024 + threadIdx.x;
    float sc = ((const float*)(ws + OFF_SSCORE))[p];
    u64 word = __ballot(sc >= SCORE_T);
    if ((threadIdx.x & 63) == 0) {
        int w = p >> 6;
        ((u64*)(ws + OFF_SVALID))[w] = word;
        ((u64*)(ws + OFF_KEEPA))[w]  = word;
        if (word) {
            int hi = 63 - __clzll(word);
            atomicMax((int*)(ws + OFF_HDR), (w << 6) + hi + 1);  // V = last valid pos + 1 = count
        }
    }
}

// ---------------- kernel 5: lower-triangle conflict bitmask ----------------
// grid (128,128), one wave per block; bit j of mask[row][w] = (iou(row, w*64+j) > 0.5) && (col < row)
extern "C" __global__ __launch_bounds__(64)
void k_mask(char* __restrict__ ws)
{
#pragma clang fp contract(off)
    const int x = blockIdx.x;                   // row chunk
    const int y = blockIdx.y;                   // col word
    if (y > x) return;                          // strictly-upper words never read
    const int V = ((const int*)(ws + OFF_HDR))[0];
    if (x * 64 >= V) return;                    // rows >= V never scanned

    const float4* obox  = (const float4*)(ws + OFF_OBOX);
    const float*  oarea = (const float*) (ws + OFF_OAREA);
    u64* mask = (u64*)(ws + OFF_MASK);

    const int lane = threadIdx.x;
    const int col  = y * 64 + lane;
    const float4 cb = obox[col];
    const float  ca = oarea[col];

    for (int r = 0; r < 64; ++r) {
        int row = x * 64 + r;
        float4 rb = obox[row];                  // wave-uniform -> broadcast
        float  ra = oarea[row];
        float ltx = fmaxf(rb.x, cb.x);
        float lty = fmaxf(rb.y, cb.y);
        float rbx = fminf(rb.z, cb.z);
        float rby = fminf(rb.w, cb.w);
        float wx = fmaxf(rbx - ltx, 0.0f);      // jnp.clip(rb-lt, 0)
        float wy = fmaxf(rby - lty, 0.0f);
        float inter = wx * wy;
        float denom = ((ra + ca) - inter) + 1e-9f;  // ref association order
        float iou = inter / denom;
        u64 m = __ballot((col < row) && (iou > IOU_T));
        if (lane == 0) mask[(size_t)row * NWORDS + y] = m;
    }
}

// ---------------- kernel 6: one fixpoint iteration ----------------
// K_out[i] = valid[i] && !(exists j<i : K_in[j] && conflict(j,i))
// Triangular recursion => iterate-t exact for chain depth <= t; unique fixed point == greedy scan.
extern "C" __global__ __launch_bounds__(1024)
void k_iter(const u64* __restrict__ kin, u64* __restrict__ kout, const char* __restrict__ ws)
{
    __shared__ u64 keep_lds[NWORDS];
    __shared__ unsigned char bits[64];
    const int tid = threadIdx.x;
    const int b   = blockIdx.x;                 // owns rows [b*64, b*64+64) == keep word b
    const int V   = ((const int*)(ws + OFF_HDR))[0];
    const u64* mask   = (const u64*)(ws + OFF_MASK);
    const u64* svalid = (const u64*)(ws + OFF_SVALID);

    if (tid < NWORDS) keep_lds[tid] = kin[tid];
    __syncthreads();

    const int w = tid >> 6, lane = tid & 63;
    const u64 vword = svalid[b];
    for (int t = 0; t < 4; ++t) {
        int rl  = w * 4 + t;                    // local row, uniform per wave
        int row = b * 64 + rl;
        int bit = 0;
        if (row < V) {
            int iw = row >> 6;                  // only words <= iw can hold j < row
            u64 acc = 0;
            if (lane <= iw)      acc  = mask[(size_t)row * NWORDS + lane]      & keep_lds[lane];
            if (lane + 64 <= iw) acc |= mask[(size_t)row * NWORDS + lane + 64] & keep_lds[lane + 64];
            bool supp = __any(acc != 0ull);
            bit = (int)((vword >> rl) & 1ull) & (supp ? 0 : 1);
        }
        if (lane == 0) bits[rl] = (unsigned char)bit;
    }
    __syncthreads();
    if (tid < 64) {
        u64 word = __ballot(bits[tid] != 0);
        if (tid == 0) kout[b] = word;
    }
}

// ---------------- kernel 7: masked outputs ----------------
// d_out (f32): boxes[8192*4] | labels[8192] | scores[8192] | keeps[8192]
extern "C" __global__ __launch_bounds__(256)
void k_out(const char* __restrict__ ws, float* __restrict__ out)
{
    const int p = blockIdx.x * 256 + threadIdx.x;
    const u64* keep = (const u64*)(ws + OFF_KEEPA);
    int kb = (int)((keep[p >> 6] >> (p & 63)) & 1ull);

    float4 bx = ((const float4*)(ws + OFF_SB))[p];
    if (!kb) bx = make_float4(0.f, 0.f, 0.f, 0.f);
    ((float4*)out)[p] = bx;
    out[M2*4 + p] = kb ? (float)((const int*)(ws + OFF_SLABEL))[p] : -1.0f;
    out[M2*5 + p] = kb ? ((const float*)(ws + OFF_SSCORE))[p] : 0.0f;
    out[M2*6 + p] = kb ? 1.0f : 0.0f;
}

extern "C" void kernel_launch(void* const* d_in, const int* in_sizes, int n_in,
                              void* d_out, int out_size, void* d_ws, size_t ws_size,
                              hipStream_t stream)
{
    const float* boxes1  = (const float*)d_in[0];
    const float* boxes2  = (const float*)d_in[1];
    const float* scores1 = (const float*)d_in[2];
    const float* scores2 = (const float*)d_in[3];
    const int*   labels1 = (const int*)d_in[4];
    const int*   labels2 = (const int*)d_in[5];
    const int*   widthp  = (const int*)d_in[6];
    char* ws = (char*)d_ws;
    u64* keepA = (u64*)(ws + OFF_KEEPA);
    u64* keepB = (u64*)(ws + OFF_KEEPB);

    hipLaunchKernelGGL(k_build, dim3(M2 / 512), dim3(512), 0, stream,
                       boxes1, boxes2, scores1, scores2, labels1, labels2, widthp, ws);
    hipLaunchKernelGGL(k_count, dim3(M2 / 256, JSPLIT), dim3(256), 0, stream, ws);
    hipLaunchKernelGGL(k_scatter, dim3(M2 / 1024), dim3(1024), 0, stream,
                       boxes1, boxes2, scores1, scores2, labels1, labels2, widthp, ws);
    hipLaunchKernelGGL(k_valid, dim3(M2 / 1024), dim3(1024), 0, stream, ws);
    hipLaunchKernelGGL(k_mask, dim3(NWORDS, NWORDS), dim3(64), 0, stream, ws);
    for (int i = 0; i < ITERS; ++i) {
        const u64* kin = (i & 1) ? keepB : keepA;
        u64*       ko  = (i & 1) ? keepA : keepB;
        hipLaunchKernelGGL(k_iter, dim3(NWORDS), dim3(1024), 0, stream, kin, ko, ws);
    }
    hipLaunchKernelGGL(k_out, dim3(M2 / 256), dim3(256), 0, stream, ws, (float*)d_out);
}